// Round 1
// baseline (359.875 us; speedup 1.0000x reference)
//
#include <hip/hip_runtime.h>
#include <hip/hip_bf16.h>
#include <math.h>

#define B_ 64
#define S_ 512
#define VEC_ 768
#define H_ 256
#define M_ (B_*S_)   // 32768

typedef float floatx4 __attribute__((ext_vector_type(4)));
typedef __bf16 bf16x8 __attribute__((ext_vector_type(8)));
typedef __bf16 bf16x4 __attribute__((ext_vector_type(4)));

#define AS_STRIDE 40  // 128x32 tile rows padded to 40 bf16 (80B): 16B-aligned ds_read_b128, 2-way banks (free)

// GEMM: C[m,n] = relu( sum_k A[m,k]*W[n,k] + mlp_b[n] ), A in {output_1,output_2} per blockIdx.z.
// tensor 0: store rows to o1 ws; both tensors: accumulate per-doc column sums.
__global__ __launch_bounds__(256) void gemm_doc_kernel(
    const float* __restrict__ out1, const float* __restrict__ out2,
    const float* __restrict__ mlp_w, const float* __restrict__ mlp_b,
    float* __restrict__ o1, float* __restrict__ sum1, float* __restrict__ sum2)
{
  __shared__ __align__(16) __bf16 As[128*AS_STRIDE];
  __shared__ __align__(16) __bf16 Bs[128*AS_STRIDE];

  const int tensor = blockIdx.z;
  const float* __restrict__ A = tensor ? out2 : out1;
  float* __restrict__ dsum = tensor ? sum2 : sum1;

  const int n0 = blockIdx.x * 128;
  const int m0 = blockIdx.y * 128;
  const int bidx = m0 >> 9;  // 512 rows per doc, tiles never straddle docs

  const int t = threadIdx.x;
  const int lane = t & 63;
  const int wave = t >> 6;
  const int q = lane >> 4;
  const int c = lane & 15;
  const int wm = (wave >> 1) * 64;
  const int wn = (wave & 1) * 64;

  floatx4 acc[4][4];
  for (int i = 0; i < 4; i++)
    for (int j = 0; j < 4; j++)
      acc[i][j] = (floatx4){0.f, 0.f, 0.f, 0.f};

  for (int k0 = 0; k0 < VEC_; k0 += 32) {
    // stage 128x32 tiles of A and W, f32 -> bf16
    for (int l = t; l < 1024; l += 256) {
      const int row = l >> 3, c4 = (l & 7) * 4;
      const float4 av = *(const float4*)&A[(size_t)(m0 + row) * VEC_ + k0 + c4];
      bf16x4 ab = { (__bf16)av.x, (__bf16)av.y, (__bf16)av.z, (__bf16)av.w };
      *(bf16x4*)&As[row * AS_STRIDE + c4] = ab;
      const float4 bv = *(const float4*)&mlp_w[(size_t)(n0 + row) * VEC_ + k0 + c4];
      bf16x4 bb = { (__bf16)bv.x, (__bf16)bv.y, (__bf16)bv.z, (__bf16)bv.w };
      *(bf16x4*)&Bs[row * AS_STRIDE + c4] = bb;
    }
    __syncthreads();
    bf16x8 af[4], bfr[4];
    for (int i = 0; i < 4; i++) af[i]  = *(const bf16x8*)&As[(wm + i*16 + c) * AS_STRIDE + q*8];
    for (int j = 0; j < 4; j++) bfr[j] = *(const bf16x8*)&Bs[(wn + j*16 + c) * AS_STRIDE + q*8];
    for (int i = 0; i < 4; i++)
      for (int j = 0; j < 4; j++)
        acc[i][j] = __builtin_amdgcn_mfma_f32_16x16x32_bf16(af[i], bfr[j], acc[i][j], 0, 0, 0);
    __syncthreads();
  }

  // epilogue: bias + relu, store (tensor 0), column sums -> atomicAdd into doc sums
  for (int j = 0; j < 4; j++) {
    const int n = n0 + wn + j*16 + c;
    const float bias = mlp_b[n];
    float colsum = 0.f;
    for (int i = 0; i < 4; i++) {
      const int mbase = m0 + wm + i*16 + q*4;
      for (int r = 0; r < 4; r++) {
        float v = acc[i][j][r] + bias;
        v = fmaxf(v, 0.f);
        colsum += v;
        if (tensor == 0) o1[(size_t)(mbase + r) * H_ + n] = v;
      }
    }
    colsum += __shfl_down(colsum, 32);
    colsum += __shfl_down(colsum, 16);
    if (lane < 16)
      atomicAdd(&dsum[bidx * H_ + n0 + wn + j*16 + lane], colsum);
  }
}

// h = relu(fd_w @ cat(o1_doc,o2_doc) + fd_b); out[b] = sigmoid(ff_w.h + ff_b) -> att row 512
__global__ __launch_bounds__(256) void head_kernel(
    const float* __restrict__ sum1, const float* __restrict__ sum2,
    const float* __restrict__ fd_w, const float* __restrict__ fd_b,
    const float* __restrict__ ff_w, const float* __restrict__ ff_b,
    float* __restrict__ out)
{
  const int b = blockIdx.x, t = threadIdx.x;
  __shared__ __align__(16) float dc[512];
  __shared__ float red[4];
  dc[t]       = sum1[b * H_ + t] * (1.f / 512.f);
  dc[t + 256] = sum2[b * H_ + t] * (1.f / 512.f);
  __syncthreads();
  const float4* wrow = (const float4*)&fd_w[(size_t)t * 512];
  const float4* dc4  = (const float4*)dc;
  float acc = 0.f;
  for (int k = 0; k < 128; k++) {
    const float4 w = wrow[k], d = dc4[k];
    acc += w.x * d.x + w.y * d.y + w.z * d.z + w.w * d.w;
  }
  const float h = fmaxf(acc + fd_b[t], 0.f);
  float part = ff_w[t] * h;
  part += __shfl_down(part, 32);
  part += __shfl_down(part, 16);
  part += __shfl_down(part, 8);
  part += __shfl_down(part, 4);
  part += __shfl_down(part, 2);
  part += __shfl_down(part, 1);
  const int lane = t & 63, wave = t >> 6;
  if (lane == 0) red[wave] = part;
  __syncthreads();
  if (t == 0) {
    const float tot = red[0] + red[1] + red[2] + red[3] + ff_b[0];
    out[(size_t)512 * 64 + b] = 1.f / (1.f + expf(-tot));
  }
}

// logits[b,s] = o1[b,s,:] . o2_doc[b,:]  (s<512);  logits[b,512] = o1_doc . o2_doc
__global__ __launch_bounds__(256) void logits_kernel(
    const float* __restrict__ o1, const float* __restrict__ sum1,
    const float* __restrict__ sum2, float* __restrict__ lg)
{
  const int b = blockIdx.y;
  const int schunk = blockIdx.x;  // 0..7, 64 s-rows each
  const int t = threadIdx.x, lane = t & 63, wave = t >> 6;
  __shared__ __align__(16) float o2d[256];
  if (t < 256) o2d[t] = sum2[b * H_ + t] * (1.f / 512.f);
  __syncthreads();
  const float4* o2d4 = (const float4*)o2d;
  const float4 w = o2d4[lane];
  const int sbase = schunk * 64;
  for (int s = sbase + wave; s < sbase + 64; s += 4) {
    const float4* row = (const float4*)&o1[((size_t)b * S_ + s) * H_];
    const float4 x = row[lane];
    float p = x.x * w.x + x.y * w.y + x.z * w.z + x.w * w.w;
    p += __shfl_down(p, 32); p += __shfl_down(p, 16); p += __shfl_down(p, 8);
    p += __shfl_down(p, 4);  p += __shfl_down(p, 2);  p += __shfl_down(p, 1);
    if (lane == 0) lg[b * 513 + s] = p;
  }
  if (schunk == 0 && wave == 0) {
    const float4* s14 = (const float4*)&sum1[b * H_];
    const float4 x = s14[lane];
    float p = (x.x * w.x + x.y * w.y + x.z * w.z + x.w * w.w) * (1.f / 512.f);
    p += __shfl_down(p, 32); p += __shfl_down(p, 16); p += __shfl_down(p, 8);
    p += __shfl_down(p, 4);  p += __shfl_down(p, 2);  p += __shfl_down(p, 1);
    if (lane == 0) lg[b * 513 + 512] = p;
  }
}

// softmax over the 513 logits per b; write rows 0..511 of att (row 512 comes from head_kernel)
__global__ __launch_bounds__(256) void softmax_kernel(
    const float* __restrict__ lg, float* __restrict__ out)
{
  const int b = blockIdx.x, t = threadIdx.x, lane = t & 63, wave = t >> 6;
  __shared__ float sl[513];
  __shared__ float r1[4], r2[4];
  for (int i = t; i < 513; i += 256) sl[i] = lg[b * 513 + i];
  __syncthreads();
  float m = -1e30f;
  for (int i = t; i < 513; i += 256) m = fmaxf(m, sl[i]);
  m = fmaxf(m, __shfl_down(m, 32)); m = fmaxf(m, __shfl_down(m, 16));
  m = fmaxf(m, __shfl_down(m, 8));  m = fmaxf(m, __shfl_down(m, 4));
  m = fmaxf(m, __shfl_down(m, 2));  m = fmaxf(m, __shfl_down(m, 1));
  if (lane == 0) r1[wave] = m;
  __syncthreads();
  m = fmaxf(fmaxf(r1[0], r1[1]), fmaxf(r1[2], r1[3]));
  float psum = 0.f;
  for (int i = t; i < 513; i += 256) { const float e = expf(sl[i] - m); sl[i] = e; psum += e; }
  psum += __shfl_down(psum, 32); psum += __shfl_down(psum, 16); psum += __shfl_down(psum, 8);
  psum += __shfl_down(psum, 4);  psum += __shfl_down(psum, 2);  psum += __shfl_down(psum, 1);
  if (lane == 0) r2[wave] = psum;
  __syncthreads();
  const float inv = 1.f / (r2[0] + r2[1] + r2[2] + r2[3]);
  for (int s = t; s < 512; s += 256) out[s * 64 + b] = sl[s] * inv;
}

extern "C" void kernel_launch(void* const* d_in, const int* in_sizes, int n_in,
                              void* d_out, int out_size, void* d_ws, size_t ws_size,
                              hipStream_t stream) {
  const float* out1  = (const float*)d_in[0];
  const float* out2  = (const float*)d_in[1];
  const float* mlp_w = (const float*)d_in[2];
  const float* mlp_b = (const float*)d_in[3];
  const float* fd_w  = (const float*)d_in[4];
  const float* fd_b  = (const float*)d_in[5];
  const float* ff_w  = (const float*)d_in[6];
  const float* ff_b  = (const float*)d_in[7];
  float* out = (float*)d_out;

  float* o1  = (float*)d_ws;                 // 32768*256 f32 = 33.55 MB
  float* s1  = o1 + (size_t)M_ * H_;         // 64*256
  float* s2  = s1 + B_ * H_;                 // 64*256
  float* lgw = s2 + B_ * H_;                 // 64*513

  hipMemsetAsync(s1, 0, 2 * B_ * H_ * sizeof(float), stream);
  gemm_doc_kernel<<<dim3(2, 256, 2), 256, 0, stream>>>(out1, out2, mlp_w, mlp_b, o1, s1, s2);
  head_kernel<<<B_, 256, 0, stream>>>(s1, s2, fd_w, fd_b, ff_w, ff_b, out);
  logits_kernel<<<dim3(8, B_), 256, 0, stream>>>(o1, s1, s2, lgw);
  softmax_kernel<<<B_, 256, 0, stream>>>(lgw, out);
}

// Round 2
// 284.152 us; speedup vs baseline: 1.2665x; 1.2665x over previous
//
#include <hip/hip_runtime.h>
#include <hip/hip_bf16.h>
#include <math.h>

#define B_ 64
#define S_ 512
#define VEC_ 768
#define H_ 256
#define M_ (B_*S_)   // 32768

typedef float floatx4 __attribute__((ext_vector_type(4)));
typedef __bf16 bf16x8 __attribute__((ext_vector_type(8)));
typedef __bf16 bf16x4 __attribute__((ext_vector_type(4)));

#define STRIDE 40  // LDS row stride in bf16: 80 B, keeps 16-B alignment for b128 frag reads

// prep: cast mlp_w (f32 [256,768]) -> bf16, zero doc-sum accumulators
__global__ __launch_bounds__(256) void prep_kernel(
    const float* __restrict__ mlp_w, __bf16* __restrict__ wbf, float* __restrict__ sums)
{
  const int bid = blockIdx.x;
  if (bid < 192) {
    const int i = bid * 256 + threadIdx.x;           // float4 index, 49152 total
    const float4 v = ((const float4*)mlp_w)[i];
    bf16x4 b = { (__bf16)v.x, (__bf16)v.y, (__bf16)v.z, (__bf16)v.w };
    *(bf16x4*)&wbf[(size_t)i * 4] = b;
  } else {
    const int i = (bid - 192) * 256 + threadIdx.x;   // 8192 float4 = 2*64*256 f32
    ((float4*)sums)[i] = make_float4(0.f, 0.f, 0.f, 0.f);
  }
}

// GEMM: C[m,n] = relu(sum_k A[m,k]*W[n,k] + mlp_b[n]); A = output_1/output_2 per blockIdx.z.
// Register-prefetched staging (1 K-iter ahead), W pre-cast to bf16, o1 stored bf16.
__global__ __launch_bounds__(256) void gemm_doc_kernel(
    const float* __restrict__ out1, const float* __restrict__ out2,
    const __bf16* __restrict__ wbf, const float* __restrict__ mlp_b,
    __bf16* __restrict__ o1, float* __restrict__ sum1, float* __restrict__ sum2)
{
  __shared__ __align__(16) __bf16 As[128 * STRIDE];
  __shared__ __align__(16) __bf16 Bs[128 * STRIDE];

  const int tensor = blockIdx.z;
  const float* __restrict__ A = tensor ? out2 : out1;
  float* __restrict__ dsum = tensor ? sum2 : sum1;

  const int n0 = blockIdx.x * 128;
  const int m0 = blockIdx.y * 128;
  const int bidx = m0 >> 9;  // 512 rows per doc; tiles never straddle docs

  const int t = threadIdx.x;
  const int lane = t & 63;
  const int wave = t >> 6;
  const int q = lane >> 4;
  const int c = lane & 15;
  const int wm = (wave >> 1) * 64;
  const int wn = (wave & 1) * 64;

  floatx4 acc[4][4];
  for (int i = 0; i < 4; i++)
    for (int j = 0; j < 4; j++)
      acc[i][j] = (floatx4){0.f, 0.f, 0.f, 0.f};

  // A staging: 1024 float4-chunks per 128x32 tile; thread t owns chunks t+i*256.
  //   chunk ch: row = ch>>3, col4 = (ch&7)*4
  // B staging: 512 bf16x8-chunks per 128x32 tile; thread t owns chunks t, t+256.
  //   chunk ch: row = ch>>2, col8 = (ch&3)*8
  float4 aR[4];
  bf16x8 bR[2];

  {  // prologue prefetch k0 = 0
    const float* Ab = &A[(size_t)m0 * VEC_];
    const __bf16* Wb = &wbf[(size_t)n0 * VEC_];
#pragma unroll
    for (int i = 0; i < 4; i++) {
      const int ch = t + i * 256;
      aR[i] = *(const float4*)&Ab[(size_t)(ch >> 3) * VEC_ + (ch & 7) * 4];
    }
#pragma unroll
    for (int i = 0; i < 2; i++) {
      const int ch = t + i * 256;
      bR[i] = *(const bf16x8*)&Wb[(size_t)(ch >> 2) * VEC_ + (ch & 3) * 8];
    }
  }

#pragma unroll 1
  for (int k0 = 0; k0 < VEC_; k0 += 32) {
    // store staged tile k0 (waits on prefetched regs; slack = previous MFMA phase)
#pragma unroll
    for (int i = 0; i < 4; i++) {
      const int ch = t + i * 256;
      bf16x4 v = { (__bf16)aR[i].x, (__bf16)aR[i].y, (__bf16)aR[i].z, (__bf16)aR[i].w };
      *(bf16x4*)&As[(ch >> 3) * STRIDE + (ch & 7) * 4] = v;
    }
#pragma unroll
    for (int i = 0; i < 2; i++) {
      const int ch = t + i * 256;
      *(bf16x8*)&Bs[(ch >> 2) * STRIDE + (ch & 3) * 8] = bR[i];
    }
    // prefetch tile k0+32 (pure loads, consumed next iteration)
    if (k0 + 32 < VEC_) {
      const float* Ab = &A[(size_t)m0 * VEC_ + k0 + 32];
      const __bf16* Wb = &wbf[(size_t)n0 * VEC_ + k0 + 32];
#pragma unroll
      for (int i = 0; i < 4; i++) {
        const int ch = t + i * 256;
        aR[i] = *(const float4*)&Ab[(size_t)(ch >> 3) * VEC_ + (ch & 7) * 4];
      }
#pragma unroll
      for (int i = 0; i < 2; i++) {
        const int ch = t + i * 256;
        bR[i] = *(const bf16x8*)&Wb[(size_t)(ch >> 2) * VEC_ + (ch & 3) * 8];
      }
    }
    __syncthreads();
    bf16x8 af[4], bfr[4];
#pragma unroll
    for (int i = 0; i < 4; i++) af[i]  = *(const bf16x8*)&As[(wm + i * 16 + c) * STRIDE + q * 8];
#pragma unroll
    for (int j = 0; j < 4; j++) bfr[j] = *(const bf16x8*)&Bs[(wn + j * 16 + c) * STRIDE + q * 8];
#pragma unroll
    for (int i = 0; i < 4; i++)
#pragma unroll
      for (int j = 0; j < 4; j++)
        acc[i][j] = __builtin_amdgcn_mfma_f32_16x16x32_bf16(af[i], bfr[j], acc[i][j], 0, 0, 0);
    __syncthreads();
  }

  // epilogue: bias + relu, store bf16 (tensor 0), column sums -> atomicAdd doc sums
#pragma unroll
  for (int j = 0; j < 4; j++) {
    const int n = n0 + wn + j * 16 + c;
    const float bias = mlp_b[n];
    float colsum = 0.f;
#pragma unroll
    for (int i = 0; i < 4; i++) {
      const int mbase = m0 + wm + i * 16 + q * 4;
#pragma unroll
      for (int r = 0; r < 4; r++) {
        float v = acc[i][j][r] + bias;
        v = fmaxf(v, 0.f);
        colsum += v;
        if (tensor == 0) o1[(size_t)(mbase + r) * H_ + n] = (__bf16)v;
      }
    }
    colsum += __shfl_down(colsum, 32);
    colsum += __shfl_down(colsum, 16);
    if (lane < 16)
      atomicAdd(&dsum[bidx * H_ + n0 + wn + j * 16 + lane], colsum);
  }
}

// logits[b,s] = o1[b,s,:] . o2_doc[b,:]  (s<512);  logits[b,512] = o1_doc . o2_doc
__global__ __launch_bounds__(256) void logits_kernel(
    const __bf16* __restrict__ o1, const float* __restrict__ sum1,
    const float* __restrict__ sum2, float* __restrict__ lg)
{
  const int b = blockIdx.y;
  const int schunk = blockIdx.x;  // 0..7, 64 s-rows each
  const int t = threadIdx.x, lane = t & 63, wave = t >> 6;
  __shared__ __align__(16) float o2d[256];
  if (t < 256) o2d[t] = sum2[b * H_ + t] * (1.f / 512.f);
  __syncthreads();
  const float4 w = ((const float4*)o2d)[lane];
  const int sbase = schunk * 64;
  for (int s = sbase + wave; s < sbase + 64; s += 4) {
    const bf16x4 x = *(const bf16x4*)&o1[((size_t)b * S_ + s) * H_ + lane * 4];
    float p = (float)x[0] * w.x + (float)x[1] * w.y + (float)x[2] * w.z + (float)x[3] * w.w;
    p += __shfl_down(p, 32); p += __shfl_down(p, 16); p += __shfl_down(p, 8);
    p += __shfl_down(p, 4);  p += __shfl_down(p, 2);  p += __shfl_down(p, 1);
    if (lane == 0) lg[b * 513 + s] = p;
  }
  if (schunk == 0 && wave == 0) {
    const float4 x = ((const float4*)&sum1[b * H_])[lane];
    float p = (x.x * w.x + x.y * w.y + x.z * w.z + x.w * w.w) * (1.f / 512.f);
    p += __shfl_down(p, 32); p += __shfl_down(p, 16); p += __shfl_down(p, 8);
    p += __shfl_down(p, 4);  p += __shfl_down(p, 2);  p += __shfl_down(p, 1);
    if (lane == 0) lg[b * 513 + 512] = p;
  }
}

// fused: MLP head (row 512 of att) + softmax over 513 logits (rows 0..511)
__global__ __launch_bounds__(256) void softmax_head_kernel(
    const float* __restrict__ lg, const float* __restrict__ sum1, const float* __restrict__ sum2,
    const float* __restrict__ fd_w, const float* __restrict__ fd_b,
    const float* __restrict__ ff_w, const float* __restrict__ ff_b,
    float* __restrict__ out)
{
  const int b = blockIdx.x, t = threadIdx.x, lane = t & 63, wave = t >> 6;
  __shared__ __align__(16) float dc[512];
  __shared__ float sl[513];
  __shared__ float red[4], r1[4], r2[4];

  // --- head: h = relu(fd_w @ cat(o1_doc,o2_doc) + fd_b); out[512,b] = sigmoid(ff_w.h + ff_b)
  dc[t]       = sum1[b * H_ + t] * (1.f / 512.f);
  dc[t + 256] = sum2[b * H_ + t] * (1.f / 512.f);
  for (int i = t; i < 513; i += 256) sl[i] = lg[b * 513 + i];
  __syncthreads();
  const float4* wrow = (const float4*)&fd_w[(size_t)t * 512];
  const float4* dc4  = (const float4*)dc;
  float acc = 0.f;
  for (int k = 0; k < 128; k++) {
    const float4 w = wrow[k], d = dc4[k];
    acc += w.x * d.x + w.y * d.y + w.z * d.z + w.w * d.w;
  }
  const float h = fmaxf(acc + fd_b[t], 0.f);
  float part = ff_w[t] * h;
  part += __shfl_down(part, 32); part += __shfl_down(part, 16);
  part += __shfl_down(part, 8);  part += __shfl_down(part, 4);
  part += __shfl_down(part, 2);  part += __shfl_down(part, 1);
  if (lane == 0) red[wave] = part;

  // --- softmax over sl[0..512]
  float m = -1e30f;
  for (int i = t; i < 513; i += 256) m = fmaxf(m, sl[i]);
  m = fmaxf(m, __shfl_down(m, 32)); m = fmaxf(m, __shfl_down(m, 16));
  m = fmaxf(m, __shfl_down(m, 8));  m = fmaxf(m, __shfl_down(m, 4));
  m = fmaxf(m, __shfl_down(m, 2));  m = fmaxf(m, __shfl_down(m, 1));
  if (lane == 0) r1[wave] = m;
  __syncthreads();
  m = fmaxf(fmaxf(r1[0], r1[1]), fmaxf(r1[2], r1[3]));
  float psum = 0.f;
  for (int i = t; i < 513; i += 256) { const float e = expf(sl[i] - m); sl[i] = e; psum += e; }
  psum += __shfl_down(psum, 32); psum += __shfl_down(psum, 16); psum += __shfl_down(psum, 8);
  psum += __shfl_down(psum, 4);  psum += __shfl_down(psum, 2);  psum += __shfl_down(psum, 1);
  if (lane == 0) r2[wave] = psum;
  __syncthreads();
  const float inv = 1.f / (r2[0] + r2[1] + r2[2] + r2[3]);
  for (int s = t; s < 512; s += 256) out[s * 64 + b] = sl[s] * inv;
  if (t == 0) {
    const float tot = red[0] + red[1] + red[2] + red[3] + ff_b[0];
    out[(size_t)512 * 64 + b] = 1.f / (1.f + expf(-tot));
  }
}

extern "C" void kernel_launch(void* const* d_in, const int* in_sizes, int n_in,
                              void* d_out, int out_size, void* d_ws, size_t ws_size,
                              hipStream_t stream) {
  const float* out1  = (const float*)d_in[0];
  const float* out2  = (const float*)d_in[1];
  const float* mlp_w = (const float*)d_in[2];
  const float* mlp_b = (const float*)d_in[3];
  const float* fd_w  = (const float*)d_in[4];
  const float* fd_b  = (const float*)d_in[5];
  const float* ff_w  = (const float*)d_in[6];
  const float* ff_b  = (const float*)d_in[7];
  float* out = (float*)d_out;

  __bf16* o1  = (__bf16*)d_ws;                       // 32768*256 bf16 = 16.78 MB
  __bf16* wbf = o1 + (size_t)M_ * H_;                // 256*768 bf16
  float*  s1  = (float*)(wbf + (size_t)H_ * VEC_);   // 64*256 f32
  float*  s2  = s1 + B_ * H_;                        // 64*256 f32
  float*  lgw = s2 + B_ * H_;                        // 64*513 f32

  prep_kernel<<<224, 256, 0, stream>>>(mlp_w, wbf, s1);
  gemm_doc_kernel<<<dim3(2, 256, 2), 256, 0, stream>>>(out1, out2, wbf, mlp_b, o1, s1, s2);
  logits_kernel<<<dim3(8, B_), 256, 0, stream>>>(o1, s1, s2, lgw);
  softmax_head_kernel<<<B_, 256, 0, stream>>>(lgw, s1, s2, fd_w, fd_b, ff_w, ff_b, out);
}